// Round 6
// baseline (693.460 us; speedup 1.0000x reference)
//
#include <hip/hip_runtime.h>

#define F_IN 61
#define H 32

// ---------- degree / dinv ----------
__global__ __launch_bounds__(256) void deg_kernel(const int* __restrict__ ei,
                                                  int* __restrict__ deg, int E) {
    int e = blockIdx.x * 256 + threadIdx.x;
    if (e < E) atomicAdd(&deg[ei[E + e]], 1);
}

__global__ __launch_bounds__(256) void dinv_kernel(const int* __restrict__ deg,
                                                   float* __restrict__ dinv, int N) {
    int i = blockIdx.x * 256 + threadIdx.x;
    if (i < N) dinv[i] = rsqrtf((float)deg[i] + 1.0f);   // +1 self-loop
}

// ---------- exclusive scan over deg (3 kernels) ----------
__global__ __launch_bounds__(256) void scan1_kernel(const int* __restrict__ deg,
                                                    int* __restrict__ scanned,
                                                    int* __restrict__ btot, int N) {
    __shared__ int s[256];
    int tid = threadIdx.x;
    int i = blockIdx.x * 256 + tid;
    int v = (i < N) ? deg[i] : 0;
    s[tid] = v;
    __syncthreads();
    for (int off = 1; off < 256; off <<= 1) {
        int t = (tid >= off) ? s[tid - off] : 0;
        __syncthreads();
        s[tid] += t;
        __syncthreads();
    }
    if (i < N) scanned[i] = s[tid] - v;
    if (tid == 255) btot[blockIdx.x] = s[255];
}

__global__ __launch_bounds__(1024) void scan2_kernel(int* __restrict__ btot, int nB) {
    __shared__ int s[1024];
    int tid = threadIdx.x;
    int v = (tid < nB) ? btot[tid] : 0;
    s[tid] = v;
    __syncthreads();
    for (int off = 1; off < 1024; off <<= 1) {
        int t = (tid >= off) ? s[tid - off] : 0;
        __syncthreads();
        s[tid] += t;
        __syncthreads();
    }
    if (tid < nB) btot[tid] = s[tid] - v;
}

__global__ __launch_bounds__(256) void scan3_kernel(const int* __restrict__ scanned,
                                                    const int* __restrict__ btot,
                                                    int* __restrict__ row_start, int N, int E) {
    int i = blockIdx.x * 256 + threadIdx.x;
    if (i < N) row_start[i] = scanned[i] + btot[blockIdx.x];
    if (i == 0) row_start[N] = E;
}

// ---------- fused: scatter (4B payload, NT store) + layer-1 dense ----------
// Blocks [0,gE): CSR scatter of src only (norm folded into hs trick).
// Blocks [gE,..): h1 = x @ W1 scaled by dinv  (hs1[v] = dinv[v] * (x[v] @ W1)).
__global__ __launch_bounds__(256) void scatter_gemm1_kernel(
        const int* __restrict__ ei, const int* __restrict__ row_start,
        int* __restrict__ cursor, const float* __restrict__ dinv,
        int* __restrict__ src_sorted,
        const float* __restrict__ x, const float* __restrict__ W,
        float* __restrict__ h, int E, int N, int gE) {
    __shared__ float Ws[F_IN * H];
    __shared__ float xs[8 * F_IN];
    if ((int)blockIdx.x < gE) {
        int e = blockIdx.x * 256 + threadIdx.x;
        if (e < E) {
            int s = ei[e];
            int d = ei[E + e];
            int pos = row_start[d] + atomicAdd(&cursor[d], 1);
            __builtin_nontemporal_store(s, &src_sorted[pos]);
        }
        return;
    }
    int tid = threadIdx.x;
    for (int i = tid; i < F_IN * H; i += 256) Ws[i] = W[i];
    int nb = ((int)blockIdx.x - gE) * 8;
    int navail = N - nb; if (navail > 8) navail = 8;
    if (navail <= 0) return;
    const float* xb = x + (long long)nb * F_IN;
    for (int i = tid; i < navail * F_IN; i += 256) xs[i] = xb[i];
    __syncthreads();
    int nl = tid >> 5, f = tid & 31;
    int node = nb + nl;
    if (node < N) {
        float s = 0.f;
        #pragma unroll
        for (int k = 0; k < F_IN; k++) s += xs[nl * F_IN + k] * Ws[k * H + f];
        h[(long long)node * H + f] = s * dinv[node];
    }
}

// ---------- fused agg + GEMM (hs form) ----------
// hs[v] = dinv[v]*h[v].  X[d] = relu(dinv[d]*(sum_{src} hs[src] + hs[d]) + b)
// hout[d] = dinv[d] * (X[d] @ Wn)   (pre-scaled for the NEXT layer's agg)
// 8 nodes/block, 32 lanes per node, 4-edge unrolled scalar gathers.
__global__ __launch_bounds__(256) void agg_gemm_kernel(const int* __restrict__ row_start,
                                                       const int* __restrict__ src_sorted,
                                                       const float* __restrict__ dinv,
                                                       const float* __restrict__ hs,
                                                       const float* __restrict__ b,
                                                       const float* __restrict__ Wn,
                                                       float* __restrict__ hout, int N) {
    __shared__ float Ws[H * H];
    __shared__ float t[8 * H];
    int tid = threadIdx.x;
    for (int i = tid; i < H * H; i += 256) Ws[i] = Wn[i];
    int nl = tid >> 5, f = tid & 31;
    int node = blockIdx.x * 8 + nl;
    if (node < N) {
        float acc = hs[(long long)node * H + f];        // self-loop term
        int e0 = row_start[node], e1 = row_start[node + 1];
        int e = e0;
        for (; e + 4 <= e1; e += 4) {
            int s0 = src_sorted[e];
            int s1 = src_sorted[e + 1];
            int s2 = src_sorted[e + 2];
            int s3 = src_sorted[e + 3];
            float h0 = hs[(long long)s0 * H + f];
            float h1 = hs[(long long)s1 * H + f];
            float h2 = hs[(long long)s2 * H + f];
            float h3 = hs[(long long)s3 * H + f];
            acc += h0 + h1 + h2 + h3;
        }
        for (; e < e1; e++)
            acc += hs[(long long)src_sorted[e] * H + f];
        t[nl * H + f] = fmaxf(dinv[node] * acc + b[f], 0.f);
    }
    __syncthreads();
    if (node < N) {
        float s = 0.f;
        #pragma unroll
        for (int k = 0; k < H; k++) s += t[nl * H + k] * Ws[k * H + f];
        hout[(long long)node * H + f] = s * dinv[node];
    }
}

// ---------- final layer: X5 = relu(...), pool into 64 spread copies ----------
__global__ __launch_bounds__(256) void agg_pool_kernel(const int* __restrict__ row_start,
                                                       const int* __restrict__ src_sorted,
                                                       const float* __restrict__ dinv,
                                                       const float* __restrict__ hs,
                                                       const float* __restrict__ b,
                                                       float* __restrict__ gs, int N) {
    __shared__ float t[8 * H];
    int tid = threadIdx.x;
    int nl = tid >> 5, f = tid & 31;
    int node = blockIdx.x * 8 + nl;
    float val = 0.f;
    if (node < N) {
        float acc = hs[(long long)node * H + f];
        int e0 = row_start[node], e1 = row_start[node + 1];
        int e = e0;
        for (; e + 4 <= e1; e += 4) {
            int s0 = src_sorted[e];
            int s1 = src_sorted[e + 1];
            int s2 = src_sorted[e + 2];
            int s3 = src_sorted[e + 3];
            acc += hs[(long long)s0 * H + f] + hs[(long long)s1 * H + f]
                 + hs[(long long)s2 * H + f] + hs[(long long)s3 * H + f];
        }
        for (; e < e1; e++)
            acc += hs[(long long)src_sorted[e] * H + f];
        val = fmaxf(dinv[node] * acc + b[f], 0.f);
    }
    t[nl * H + f] = val;
    __syncthreads();
    if (tid < H) {
        float s = 0.f;
        #pragma unroll
        for (int r = 0; r < 8; r++) s += t[r * H + tid];
        atomicAdd(&gs[(blockIdx.x & 63) * H + tid], s);
    }
}

// ---------- head: reduce 64 pool copies, 32->16 relu, 16->3 ----------
__global__ __launch_bounds__(64) void head_kernel(const float* __restrict__ gs,
                                                  const float* __restrict__ Wl1,
                                                  const float* __restrict__ bl1,
                                                  const float* __restrict__ Wl2,
                                                  const float* __restrict__ bl2,
                                                  float* __restrict__ out) {
    __shared__ float gg[H];
    __shared__ float t[16];
    int tid = threadIdx.x;
    if (tid < H) {
        float s = 0.f;
        for (int c = 0; c < 64; c++) s += gs[c * H + tid];
        gg[tid] = s;
    }
    __syncthreads();
    if (tid < 16) {
        float s = bl1[tid];
        #pragma unroll
        for (int k = 0; k < 32; k++) s += gg[k] * Wl1[k * 16 + tid];
        t[tid] = fmaxf(s, 0.f);
    }
    __syncthreads();
    if (tid < 3) {
        float s = bl2[tid];
        #pragma unroll
        for (int k = 0; k < 16; k++) s += t[k] * Wl2[k * 3 + tid];
        out[tid] = s;
    }
}

extern "C" void kernel_launch(void* const* d_in, const int* in_sizes, int n_in,
                              void* d_out, int out_size, void* d_ws, size_t ws_size,
                              hipStream_t stream) {
    const float* x   = (const float*)d_in[0];
    const int*   ei  = (const int*)d_in[1];
    const float* W1  = (const float*)d_in[2];
    const float* b1  = (const float*)d_in[3];
    const float* W2  = (const float*)d_in[4];
    const float* b2  = (const float*)d_in[5];
    const float* W3  = (const float*)d_in[6];
    const float* b3  = (const float*)d_in[7];
    const float* W4  = (const float*)d_in[8];
    const float* b4  = (const float*)d_in[9];
    const float* Wl1 = (const float*)d_in[10];
    const float* bl1 = (const float*)d_in[11];
    const float* Wl2 = (const float*)d_in[12];
    const float* bl2 = (const float*)d_in[13];
    float* out = (float*)d_out;

    const int N = in_sizes[0] / F_IN;
    const int E = in_sizes[1] / 2;

    char* ws = (char*)d_ws;
    size_t off = 0;
    auto alloc = [&](size_t bytes) {
        char* p = ws + off;
        off += (bytes + 255) & ~(size_t)255;
        return p;
    };
    int*   deg        = (int*)alloc((size_t)N * 4);
    float* dinv       = (float*)alloc((size_t)N * 4);
    int*   scanned    = (int*)alloc((size_t)N * 4);
    int*   btot       = (int*)alloc(((size_t)N / 256 + 2) * 4);
    int*   row_start  = (int*)alloc((size_t)(N + 1) * 4);
    int*   cursor     = (int*)alloc((size_t)N * 4);
    int*   src_sorted = (int*)alloc((size_t)E * 4);
    float* bufA       = (float*)alloc((size_t)N * H * 4);
    float* bufB       = (float*)alloc((size_t)N * H * 4);
    float* gs         = (float*)alloc(64 * H * 4);

    const int TB = 256;
    const int gE  = (E + TB - 1) / TB;
    const int gN  = (N + TB - 1) / TB;   // scan blocks (<=1024 for N<=262144)
    const int gN8 = (N + 7) / 8;

    // ---- CSR build ----
    hipMemsetAsync(deg, 0, (size_t)N * 4, stream);
    hipMemsetAsync(cursor, 0, (size_t)N * 4, stream);
    hipMemsetAsync(gs, 0, 64 * H * 4, stream);
    deg_kernel<<<gE, TB, 0, stream>>>(ei, deg, E);
    dinv_kernel<<<gN, TB, 0, stream>>>(deg, dinv, N);
    scan1_kernel<<<gN, TB, 0, stream>>>(deg, scanned, btot, N);
    scan2_kernel<<<1, 1024, 0, stream>>>(btot, gN);
    scan3_kernel<<<gN, TB, 0, stream>>>(scanned, btot, row_start, N, E);

    // ---- scatter + layer-1 dense fused (independent work, overlaps) ----
    scatter_gemm1_kernel<<<gE + gN8, TB, 0, stream>>>(ei, row_start, cursor, dinv,
                                                      src_sorted, x, W1, bufA, E, N, gE);

    // ---- layers 2..4 fused agg+GEMM, final agg+pool ----
    agg_gemm_kernel<<<gN8, TB, 0, stream>>>(row_start, src_sorted, dinv, bufA, b1, W2, bufB, N);
    agg_gemm_kernel<<<gN8, TB, 0, stream>>>(row_start, src_sorted, dinv, bufB, b2, W3, bufA, N);
    agg_gemm_kernel<<<gN8, TB, 0, stream>>>(row_start, src_sorted, dinv, bufA, b3, W4, bufB, N);
    agg_pool_kernel<<<gN8, TB, 0, stream>>>(row_start, src_sorted, dinv, bufB, b4, gs, N);

    head_kernel<<<1, 64, 0, stream>>>(gs, Wl1, bl1, Wl2, bl2, out);
}

// Round 7
// 601.637 us; speedup vs baseline: 1.1526x; 1.1526x over previous
//
#include <hip/hip_runtime.h>

#define F_IN 61
#define H 32

// ---------- degree / dinv ----------
__global__ __launch_bounds__(256) void deg_kernel(const int* __restrict__ ei,
                                                  int* __restrict__ deg, int E) {
    int e = blockIdx.x * 256 + threadIdx.x;
    if (e < E) atomicAdd(&deg[ei[E + e]], 1);
}

__global__ __launch_bounds__(256) void dinv_kernel(const int* __restrict__ deg,
                                                   float* __restrict__ dinv, int N) {
    int i = blockIdx.x * 256 + threadIdx.x;
    if (i < N) dinv[i] = rsqrtf((float)deg[i] + 1.0f);   // +1 self-loop
}

// ---------- exclusive scan over deg (3 kernels) ----------
__global__ __launch_bounds__(256) void scan1_kernel(const int* __restrict__ deg,
                                                    int* __restrict__ scanned,
                                                    int* __restrict__ btot, int N) {
    __shared__ int s[256];
    int tid = threadIdx.x;
    int i = blockIdx.x * 256 + tid;
    int v = (i < N) ? deg[i] : 0;
    s[tid] = v;
    __syncthreads();
    for (int off = 1; off < 256; off <<= 1) {
        int t = (tid >= off) ? s[tid - off] : 0;
        __syncthreads();
        s[tid] += t;
        __syncthreads();
    }
    if (i < N) scanned[i] = s[tid] - v;
    if (tid == 255) btot[blockIdx.x] = s[255];
}

__global__ __launch_bounds__(1024) void scan2_kernel(int* __restrict__ btot, int nB) {
    __shared__ int s[1024];
    int tid = threadIdx.x;
    int v = (tid < nB) ? btot[tid] : 0;
    s[tid] = v;
    __syncthreads();
    for (int off = 1; off < 1024; off <<= 1) {
        int t = (tid >= off) ? s[tid - off] : 0;
        __syncthreads();
        s[tid] += t;
        __syncthreads();
    }
    if (tid < nB) btot[tid] = s[tid] - v;
}

__global__ __launch_bounds__(256) void scan3_kernel(const int* __restrict__ scanned,
                                                    const int* __restrict__ btot,
                                                    int* __restrict__ row_start, int N, int E) {
    int i = blockIdx.x * 256 + threadIdx.x;
    if (i < N) row_start[i] = scanned[i] + btot[blockIdx.x];
    if (i == 0) row_start[N] = E;
}

// ---------- scatter: 4B src payload only ----------
__global__ __launch_bounds__(256) void scatter_kernel(const int* __restrict__ ei,
                                                      const int* __restrict__ row_start,
                                                      int* __restrict__ cursor,
                                                      int* __restrict__ src_sorted, int E) {
    int e = blockIdx.x * 256 + threadIdx.x;
    if (e < E) {
        int s = ei[e];
        int d = ei[E + e];
        int pos = row_start[d] + atomicAdd(&cursor[d], 1);
        src_sorted[pos] = s;
    }
}

// ---------- layer 1 dense: hs1 = dinv * (x @ W1) ----------
__global__ __launch_bounds__(256) void gemm1_kernel(const float* __restrict__ x,
                                                    const float* __restrict__ W,
                                                    const float* __restrict__ dinv,
                                                    float* __restrict__ h, int N) {
    __shared__ float Ws[F_IN * H];
    __shared__ float xs[8 * F_IN];
    int tid = threadIdx.x;
    for (int i = tid; i < F_IN * H; i += 256) Ws[i] = W[i];
    int nb = blockIdx.x * 8;
    int navail = N - nb; if (navail > 8) navail = 8;
    const float* xb = x + (long long)nb * F_IN;
    for (int i = tid; i < navail * F_IN; i += 256) xs[i] = xb[i];
    __syncthreads();
    int nl = tid >> 5, f = tid & 31;
    int node = nb + nl;
    if (node < N) {
        float s = 0.f;
        #pragma unroll
        for (int k = 0; k < F_IN; k++) s += xs[nl * F_IN + k] * Ws[k * H + f];
        h[(long long)node * H + f] = s * dinv[node];
    }
}

// ---------- fused agg + GEMM (hs form, deep gather pipeline) ----------
// hs[v] = dinv[v]*h[v].  X[d] = relu(dinv[d]*(sum_{src} hs[src] + hs[d]) + b)
// hout[d] = dinv[d] * (X[d] @ Wn)
// 8 nodes/block, 32 lanes per node. The 32 lanes coalesced-load 32 edge
// indices in ONE instruction, then __shfl-broadcast them into batches of 8
// independent row-gathers in flight (breaks the idx->gather latency chain).
__global__ __launch_bounds__(256) void agg_gemm_kernel(const int* __restrict__ row_start,
                                                       const int* __restrict__ src_sorted,
                                                       const float* __restrict__ dinv,
                                                       const float* __restrict__ hs,
                                                       const float* __restrict__ b,
                                                       const float* __restrict__ Wn,
                                                       float* __restrict__ hout, int N) {
    __shared__ float Ws[H * H];
    __shared__ float t[8 * H];
    int tid = threadIdx.x;
    for (int i = tid; i < H * H; i += 256) Ws[i] = Wn[i];
    int nl = tid >> 5, f = tid & 31;
    int node = blockIdx.x * 8 + nl;
    if (node < N) {
        float acc = hs[(long long)node * H + f];          // self-loop term
        int e0 = row_start[node], e1 = row_start[node + 1];
        for (int base = e0; base < e1; base += 32) {
            int rem = e1 - base;
            int cnt = rem < 32 ? rem : 32;
            int idx = 0;
            if (f < rem) idx = src_sorted[base + f];      // coalesced, 1 instr
            for (int j = 0; j < cnt; j += 8) {
                float g[8];
                #pragma unroll
                for (int k = 0; k < 8; k++) {
                    int s = __shfl(idx, j + k, 32);       // row 0 if slot invalid
                    float v = hs[(long long)s * H + f];   // 8 gathers in flight
                    g[k] = (j + k < cnt) ? v : 0.f;
                }
                acc += ((g[0] + g[1]) + (g[2] + g[3])) + ((g[4] + g[5]) + (g[6] + g[7]));
            }
        }
        t[nl * H + f] = fmaxf(dinv[node] * acc + b[f], 0.f);
    }
    __syncthreads();
    if (node < N) {
        float s = 0.f;
        #pragma unroll
        for (int k = 0; k < H; k++) s += t[nl * H + k] * Ws[k * H + f];
        hout[(long long)node * H + f] = s * dinv[node];
    }
}

// ---------- final layer: X5 = relu(...), pool into 64 spread copies ----------
__global__ __launch_bounds__(256) void agg_pool_kernel(const int* __restrict__ row_start,
                                                       const int* __restrict__ src_sorted,
                                                       const float* __restrict__ dinv,
                                                       const float* __restrict__ hs,
                                                       const float* __restrict__ b,
                                                       float* __restrict__ gs, int N) {
    __shared__ float t[8 * H];
    int tid = threadIdx.x;
    int nl = tid >> 5, f = tid & 31;
    int node = blockIdx.x * 8 + nl;
    float val = 0.f;
    if (node < N) {
        float acc = hs[(long long)node * H + f];
        int e0 = row_start[node], e1 = row_start[node + 1];
        for (int base = e0; base < e1; base += 32) {
            int rem = e1 - base;
            int cnt = rem < 32 ? rem : 32;
            int idx = 0;
            if (f < rem) idx = src_sorted[base + f];
            for (int j = 0; j < cnt; j += 8) {
                float g[8];
                #pragma unroll
                for (int k = 0; k < 8; k++) {
                    int s = __shfl(idx, j + k, 32);
                    float v = hs[(long long)s * H + f];
                    g[k] = (j + k < cnt) ? v : 0.f;
                }
                acc += ((g[0] + g[1]) + (g[2] + g[3])) + ((g[4] + g[5]) + (g[6] + g[7]));
            }
        }
        val = fmaxf(dinv[node] * acc + b[f], 0.f);
    }
    t[nl * H + f] = val;
    __syncthreads();
    if (tid < H) {
        float s = 0.f;
        #pragma unroll
        for (int r = 0; r < 8; r++) s += t[r * H + tid];
        atomicAdd(&gs[(blockIdx.x & 63) * H + tid], s);
    }
}

// ---------- head: reduce 64 pool copies, 32->16 relu, 16->3 ----------
__global__ __launch_bounds__(64) void head_kernel(const float* __restrict__ gs,
                                                  const float* __restrict__ Wl1,
                                                  const float* __restrict__ bl1,
                                                  const float* __restrict__ Wl2,
                                                  const float* __restrict__ bl2,
                                                  float* __restrict__ out) {
    __shared__ float gg[H];
    __shared__ float t[16];
    int tid = threadIdx.x;
    if (tid < H) {
        float s = 0.f;
        for (int c = 0; c < 64; c++) s += gs[c * H + tid];
        gg[tid] = s;
    }
    __syncthreads();
    if (tid < 16) {
        float s = bl1[tid];
        #pragma unroll
        for (int k = 0; k < 32; k++) s += gg[k] * Wl1[k * 16 + tid];
        t[tid] = fmaxf(s, 0.f);
    }
    __syncthreads();
    if (tid < 3) {
        float s = bl2[tid];
        #pragma unroll
        for (int k = 0; k < 16; k++) s += t[k] * Wl2[k * 3 + tid];
        out[tid] = s;
    }
}

extern "C" void kernel_launch(void* const* d_in, const int* in_sizes, int n_in,
                              void* d_out, int out_size, void* d_ws, size_t ws_size,
                              hipStream_t stream) {
    const float* x   = (const float*)d_in[0];
    const int*   ei  = (const int*)d_in[1];
    const float* W1  = (const float*)d_in[2];
    const float* b1  = (const float*)d_in[3];
    const float* W2  = (const float*)d_in[4];
    const float* b2  = (const float*)d_in[5];
    const float* W3  = (const float*)d_in[6];
    const float* b3  = (const float*)d_in[7];
    const float* W4  = (const float*)d_in[8];
    const float* b4  = (const float*)d_in[9];
    const float* Wl1 = (const float*)d_in[10];
    const float* bl1 = (const float*)d_in[11];
    const float* Wl2 = (const float*)d_in[12];
    const float* bl2 = (const float*)d_in[13];
    float* out = (float*)d_out;

    const int N = in_sizes[0] / F_IN;
    const int E = in_sizes[1] / 2;

    char* ws = (char*)d_ws;
    size_t off = 0;
    auto alloc = [&](size_t bytes) {
        char* p = ws + off;
        off += (bytes + 255) & ~(size_t)255;
        return p;
    };
    int*   deg        = (int*)alloc((size_t)N * 4);
    float* dinv       = (float*)alloc((size_t)N * 4);
    int*   scanned    = (int*)alloc((size_t)N * 4);
    int*   btot       = (int*)alloc(((size_t)N / 256 + 2) * 4);
    int*   row_start  = (int*)alloc((size_t)(N + 1) * 4);
    int*   cursor     = (int*)alloc((size_t)N * 4);
    int*   src_sorted = (int*)alloc((size_t)E * 4);
    float* bufA       = (float*)alloc((size_t)N * H * 4);
    float* bufB       = (float*)alloc((size_t)N * H * 4);
    float* gs         = (float*)alloc(64 * H * 4);

    const int TB = 256;
    const int gE  = (E + TB - 1) / TB;
    const int gN  = (N + TB - 1) / TB;   // scan blocks (<=1024 for N<=262144)
    const int gN8 = (N + 7) / 8;

    // ---- CSR build ----
    hipMemsetAsync(deg, 0, (size_t)N * 4, stream);
    hipMemsetAsync(cursor, 0, (size_t)N * 4, stream);
    hipMemsetAsync(gs, 0, 64 * H * 4, stream);
    deg_kernel<<<gE, TB, 0, stream>>>(ei, deg, E);
    dinv_kernel<<<gN, TB, 0, stream>>>(deg, dinv, N);
    scan1_kernel<<<gN, TB, 0, stream>>>(deg, scanned, btot, N);
    scan2_kernel<<<1, 1024, 0, stream>>>(btot, gN);
    scan3_kernel<<<gN, TB, 0, stream>>>(scanned, btot, row_start, N, E);
    scatter_kernel<<<gE, TB, 0, stream>>>(ei, row_start, cursor, src_sorted, E);

    // ---- layers ----
    gemm1_kernel<<<gN8, TB, 0, stream>>>(x, W1, dinv, bufA, N);                               // hs1
    agg_gemm_kernel<<<gN8, TB, 0, stream>>>(row_start, src_sorted, dinv, bufA, b1, W2, bufB, N); // hs2
    agg_gemm_kernel<<<gN8, TB, 0, stream>>>(row_start, src_sorted, dinv, bufB, b2, W3, bufA, N); // hs3
    agg_gemm_kernel<<<gN8, TB, 0, stream>>>(row_start, src_sorted, dinv, bufA, b3, W4, bufB, N); // hs4
    agg_pool_kernel<<<gN8, TB, 0, stream>>>(row_start, src_sorted, dinv, bufB, b4, gs, N);       // pool(X5)

    head_kernel<<<1, 64, 0, stream>>>(gs, Wl1, bl1, Wl2, bl2, out);
}

// Round 8
// 600.298 us; speedup vs baseline: 1.1552x; 1.0022x over previous
//
#include <hip/hip_runtime.h>

#define F_IN 61
#define H 32
#define BUCK_BITS 12                 // 4096 nodes per bucket
#define BUCK_SZ   4096
#define CHUNK     8192               // edges per block in hist/bin passes

// ---------- degree / dinv ----------
__global__ __launch_bounds__(256) void deg_kernel(const int* __restrict__ ei,
                                                  int* __restrict__ deg, int E) {
    int e = blockIdx.x * 256 + threadIdx.x;
    if (e < E) atomicAdd(&deg[ei[E + e]], 1);
}

__global__ __launch_bounds__(256) void dinv_kernel(const int* __restrict__ deg,
                                                   float* __restrict__ dinv, int N) {
    int i = blockIdx.x * 256 + threadIdx.x;
    if (i < N) dinv[i] = rsqrtf((float)deg[i] + 1.0f);   // +1 self-loop
}

// ---------- exclusive scan over deg -> row_start ----------
__global__ __launch_bounds__(256) void scan1_kernel(const int* __restrict__ deg,
                                                    int* __restrict__ scanned,
                                                    int* __restrict__ btot, int N) {
    __shared__ int s[256];
    int tid = threadIdx.x;
    int i = blockIdx.x * 256 + tid;
    int v = (i < N) ? deg[i] : 0;
    s[tid] = v;
    __syncthreads();
    for (int off = 1; off < 256; off <<= 1) {
        int t = (tid >= off) ? s[tid - off] : 0;
        __syncthreads();
        s[tid] += t;
        __syncthreads();
    }
    if (i < N) scanned[i] = s[tid] - v;
    if (tid == 255) btot[blockIdx.x] = s[255];
}

__global__ __launch_bounds__(1024) void scan2_kernel(int* __restrict__ btot, int nB) {
    __shared__ int s[1024];
    int tid = threadIdx.x;
    int v = (tid < nB) ? btot[tid] : 0;
    s[tid] = v;
    __syncthreads();
    for (int off = 1; off < 1024; off <<= 1) {
        int t = (tid >= off) ? s[tid - off] : 0;
        __syncthreads();
        s[tid] += t;
        __syncthreads();
    }
    if (tid < nB) btot[tid] = s[tid] - v;
}

__global__ __launch_bounds__(256) void scan3_kernel(const int* __restrict__ scanned,
                                                    const int* __restrict__ btot,
                                                    int* __restrict__ row_start, int N, int E) {
    int i = blockIdx.x * 256 + threadIdx.x;
    if (i < N) row_start[i] = scanned[i] + btot[blockIdx.x];
    if (i == 0) row_start[N] = E;
}

// ---------- pass A: per-(block,bucket) histogram ----------
__global__ __launch_bounds__(256) void histA_kernel(const int* __restrict__ ei,
                                                    int* __restrict__ counts,
                                                    int E, int B, int nbuck) {
    __shared__ int h[64];
    int tid = threadIdx.x;
    if (tid < 64) h[tid] = 0;
    __syncthreads();
    int e0 = blockIdx.x * CHUNK;
    int e1 = e0 + CHUNK; if (e1 > E) e1 = E;
    for (int e = e0 + tid; e < e1; e += 256)
        atomicAdd(&h[ei[E + e] >> BUCK_BITS], 1);
    __syncthreads();
    if (tid < nbuck) counts[tid * B + blockIdx.x] = h[tid];
}

// ---------- scan of counts (bucket-major => bucket-contiguous ranges) ----------
__global__ __launch_bounds__(1024) void scanC_kernel(int* __restrict__ c, int n) {
    __shared__ int s[1024];
    __shared__ int carry;
    int tid = threadIdx.x;
    if (tid == 0) carry = 0;
    __syncthreads();
    for (int base = 0; base < n; base += 1024) {
        int v = (base + tid < n) ? c[base + tid] : 0;
        s[tid] = v;
        __syncthreads();
        for (int off = 1; off < 1024; off <<= 1) {
            int t = (tid >= off) ? s[tid - off] : 0;
            __syncthreads();
            s[tid] += t;
            __syncthreads();
        }
        int incl = s[tid];
        int cur = carry;
        if (base + tid < n) c[base + tid] = incl - v + cur;
        __syncthreads();
        if (tid == 1023) carry = cur + incl;
        __syncthreads();
    }
}

// ---------- pass B: bin edges into per-(block,bucket) EXCLUSIVE ranges ----------
// A given output line is written by exactly one block -> fills inside one L2
// before writeback (~1x write amplification). pack = (src<<12)|(dst&4095).
__global__ __launch_bounds__(256) void binB_kernel(const int* __restrict__ ei,
                                                   const int* __restrict__ counts,
                                                   int* __restrict__ tmp,
                                                   int E, int B, int nbuck) {
    __shared__ int lcur[64];
    int tid = threadIdx.x;
    if (tid < nbuck) lcur[tid] = counts[tid * B + blockIdx.x];
    __syncthreads();
    int e0 = blockIdx.x * CHUNK;
    int e1 = e0 + CHUNK; if (e1 > E) e1 = E;
    for (int e = e0 + tid; e < e1; e += 256) {
        int s = ei[e];
        int d = ei[E + e];
        int pos = atomicAdd(&lcur[d >> BUCK_BITS], 1);
        tmp[pos] = (s << BUCK_BITS) | (d & (BUCK_SZ - 1));
    }
}

// ---------- pass C: per-bucket final CSR scatter (single block per bucket) ----------
__global__ __launch_bounds__(256) void binC_kernel(const int* __restrict__ row_start,
                                                   const int* __restrict__ tmp,
                                                   int* __restrict__ src_sorted, int N) {
    __shared__ int lcur[BUCK_SZ];
    int tid = threadIdx.x;
    int base = blockIdx.x << BUCK_BITS;
    int nn = N - base; if (nn > BUCK_SZ) nn = BUCK_SZ;
    for (int i = tid; i < nn; i += 256) lcur[i] = row_start[base + i];
    __syncthreads();
    int hiNode = base + BUCK_SZ; if (hiNode > N) hiNode = N;
    int e0 = row_start[base];
    int e1 = row_start[hiNode];
    for (int e = e0 + tid; e < e1; e += 256) {
        int p = tmp[e];
        int pos = atomicAdd(&lcur[p & (BUCK_SZ - 1)], 1);
        src_sorted[pos] = p >> BUCK_BITS;
    }
}

// ---------- layer 1 dense: hs1 = dinv * (x @ W1) ----------
__global__ __launch_bounds__(256) void gemm1_kernel(const float* __restrict__ x,
                                                    const float* __restrict__ W,
                                                    const float* __restrict__ dinv,
                                                    float* __restrict__ h, int N) {
    __shared__ float Ws[F_IN * H];
    __shared__ float xs[8 * F_IN];
    int tid = threadIdx.x;
    for (int i = tid; i < F_IN * H; i += 256) Ws[i] = W[i];
    int nb = blockIdx.x * 8;
    int navail = N - nb; if (navail > 8) navail = 8;
    const float* xb = x + (long long)nb * F_IN;
    for (int i = tid; i < navail * F_IN; i += 256) xs[i] = xb[i];
    __syncthreads();
    int nl = tid >> 5, f = tid & 31;
    int node = nb + nl;
    if (node < N) {
        float s = 0.f;
        #pragma unroll
        for (int k = 0; k < F_IN; k++) s += xs[nl * F_IN + k] * Ws[k * H + f];
        h[(long long)node * H + f] = s * dinv[node];
    }
}

// ---------- fused agg + GEMM (hs form, deep gather pipeline) ----------
__global__ __launch_bounds__(256) void agg_gemm_kernel(const int* __restrict__ row_start,
                                                       const int* __restrict__ src_sorted,
                                                       const float* __restrict__ dinv,
                                                       const float* __restrict__ hs,
                                                       const float* __restrict__ b,
                                                       const float* __restrict__ Wn,
                                                       float* __restrict__ hout, int N) {
    __shared__ float Ws[H * H];
    __shared__ float t[8 * H];
    int tid = threadIdx.x;
    for (int i = tid; i < H * H; i += 256) Ws[i] = Wn[i];
    int nl = tid >> 5, f = tid & 31;
    int node = blockIdx.x * 8 + nl;
    if (node < N) {
        float acc = hs[(long long)node * H + f];          // self-loop term
        int e0 = row_start[node], e1 = row_start[node + 1];
        for (int base = e0; base < e1; base += 32) {
            int rem = e1 - base;
            int cnt = rem < 32 ? rem : 32;
            int idx = 0;
            if (f < rem) idx = src_sorted[base + f];      // coalesced, 1 instr
            for (int j = 0; j < cnt; j += 8) {
                float g[8];
                #pragma unroll
                for (int k = 0; k < 8; k++) {
                    int s = __shfl(idx, j + k, 32);       // row 0 if slot invalid
                    float v = hs[(long long)s * H + f];   // 8 gathers in flight
                    g[k] = (j + k < cnt) ? v : 0.f;
                }
                acc += ((g[0] + g[1]) + (g[2] + g[3])) + ((g[4] + g[5]) + (g[6] + g[7]));
            }
        }
        t[nl * H + f] = fmaxf(dinv[node] * acc + b[f], 0.f);
    }
    __syncthreads();
    if (node < N) {
        float s = 0.f;
        #pragma unroll
        for (int k = 0; k < H; k++) s += t[nl * H + k] * Ws[k * H + f];
        hout[(long long)node * H + f] = s * dinv[node];
    }
}

// ---------- final layer: X5 = relu(...), pool into 64 spread copies ----------
__global__ __launch_bounds__(256) void agg_pool_kernel(const int* __restrict__ row_start,
                                                       const int* __restrict__ src_sorted,
                                                       const float* __restrict__ dinv,
                                                       const float* __restrict__ hs,
                                                       const float* __restrict__ b,
                                                       float* __restrict__ gs, int N) {
    __shared__ float t[8 * H];
    int tid = threadIdx.x;
    int nl = tid >> 5, f = tid & 31;
    int node = blockIdx.x * 8 + nl;
    float val = 0.f;
    if (node < N) {
        float acc = hs[(long long)node * H + f];
        int e0 = row_start[node], e1 = row_start[node + 1];
        for (int base = e0; base < e1; base += 32) {
            int rem = e1 - base;
            int cnt = rem < 32 ? rem : 32;
            int idx = 0;
            if (f < rem) idx = src_sorted[base + f];
            for (int j = 0; j < cnt; j += 8) {
                float g[8];
                #pragma unroll
                for (int k = 0; k < 8; k++) {
                    int s = __shfl(idx, j + k, 32);
                    float v = hs[(long long)s * H + f];
                    g[k] = (j + k < cnt) ? v : 0.f;
                }
                acc += ((g[0] + g[1]) + (g[2] + g[3])) + ((g[4] + g[5]) + (g[6] + g[7]));
            }
        }
        val = fmaxf(dinv[node] * acc + b[f], 0.f);
    }
    t[nl * H + f] = val;
    __syncthreads();
    if (tid < H) {
        float s = 0.f;
        #pragma unroll
        for (int r = 0; r < 8; r++) s += t[r * H + tid];
        atomicAdd(&gs[(blockIdx.x & 63) * H + tid], s);
    }
}

// ---------- head ----------
__global__ __launch_bounds__(64) void head_kernel(const float* __restrict__ gs,
                                                  const float* __restrict__ Wl1,
                                                  const float* __restrict__ bl1,
                                                  const float* __restrict__ Wl2,
                                                  const float* __restrict__ bl2,
                                                  float* __restrict__ out) {
    __shared__ float gg[H];
    __shared__ float t[16];
    int tid = threadIdx.x;
    if (tid < H) {
        float s = 0.f;
        for (int c = 0; c < 64; c++) s += gs[c * H + tid];
        gg[tid] = s;
    }
    __syncthreads();
    if (tid < 16) {
        float s = bl1[tid];
        #pragma unroll
        for (int k = 0; k < 32; k++) s += gg[k] * Wl1[k * 16 + tid];
        t[tid] = fmaxf(s, 0.f);
    }
    __syncthreads();
    if (tid < 3) {
        float s = bl2[tid];
        #pragma unroll
        for (int k = 0; k < 16; k++) s += t[k] * Wl2[k * 3 + tid];
        out[tid] = s;
    }
}

extern "C" void kernel_launch(void* const* d_in, const int* in_sizes, int n_in,
                              void* d_out, int out_size, void* d_ws, size_t ws_size,
                              hipStream_t stream) {
    const float* x   = (const float*)d_in[0];
    const int*   ei  = (const int*)d_in[1];
    const float* W1  = (const float*)d_in[2];
    const float* b1  = (const float*)d_in[3];
    const float* W2  = (const float*)d_in[4];
    const float* b2  = (const float*)d_in[5];
    const float* W3  = (const float*)d_in[6];
    const float* b3  = (const float*)d_in[7];
    const float* W4  = (const float*)d_in[8];
    const float* b4  = (const float*)d_in[9];
    const float* Wl1 = (const float*)d_in[10];
    const float* bl1 = (const float*)d_in[11];
    const float* Wl2 = (const float*)d_in[12];
    const float* bl2 = (const float*)d_in[13];
    float* out = (float*)d_out;

    const int N = in_sizes[0] / F_IN;
    const int E = in_sizes[1] / 2;
    const int nbuck = (N + BUCK_SZ - 1) >> BUCK_BITS;      // 37 for N=150000
    const int B = (E + CHUNK - 1) / CHUNK;                 // 293 for E=2.4M

    char* ws = (char*)d_ws;
    size_t off = 0;
    auto alloc = [&](size_t bytes) {
        char* p = ws + off;
        off += (bytes + 255) & ~(size_t)255;
        return p;
    };
    int*   deg        = (int*)alloc((size_t)N * 4);
    float* dinv       = (float*)alloc((size_t)N * 4);
    int*   scanned    = (int*)alloc((size_t)N * 4);
    int*   btot       = (int*)alloc(((size_t)N / 256 + 2) * 4);
    int*   row_start  = (int*)alloc((size_t)(N + 1) * 4);
    int*   counts     = (int*)alloc((size_t)64 * B * 4);
    int*   src_sorted = (int*)alloc((size_t)E * 4);
    float* bufA       = (float*)alloc((size_t)N * H * 4);
    float* bufB       = (float*)alloc((size_t)N * H * 4);
    float* gs         = (float*)alloc(64 * H * 4);
    int*   tmp        = (int*)bufA;    // pass-B scratch; dead before gemm1 writes bufA

    const int TB = 256;
    const int gE  = (E + TB - 1) / TB;
    const int gN  = (N + TB - 1) / TB;   // scan blocks (<=1024 for N<=262144)
    const int gN8 = (N + 7) / 8;

    // ---- CSR build ----
    hipMemsetAsync(deg, 0, (size_t)N * 4, stream);
    hipMemsetAsync(gs, 0, 64 * H * 4, stream);
    deg_kernel<<<gE, TB, 0, stream>>>(ei, deg, E);
    dinv_kernel<<<gN, TB, 0, stream>>>(deg, dinv, N);
    scan1_kernel<<<gN, TB, 0, stream>>>(deg, scanned, btot, N);
    scan2_kernel<<<1, 1024, 0, stream>>>(btot, gN);
    scan3_kernel<<<gN, TB, 0, stream>>>(scanned, btot, row_start, N, E);
    histA_kernel<<<B, TB, 0, stream>>>(ei, counts, E, B, nbuck);
    scanC_kernel<<<1, 1024, 0, stream>>>(counts, nbuck * B);
    binB_kernel<<<B, TB, 0, stream>>>(ei, counts, tmp, E, B, nbuck);
    binC_kernel<<<nbuck, TB, 0, stream>>>(row_start, tmp, src_sorted, N);

    // ---- layers ----
    gemm1_kernel<<<gN8, TB, 0, stream>>>(x, W1, dinv, bufA, N);                                  // hs1
    agg_gemm_kernel<<<gN8, TB, 0, stream>>>(row_start, src_sorted, dinv, bufA, b1, W2, bufB, N); // hs2
    agg_gemm_kernel<<<gN8, TB, 0, stream>>>(row_start, src_sorted, dinv, bufB, b2, W3, bufA, N); // hs3
    agg_gemm_kernel<<<gN8, TB, 0, stream>>>(row_start, src_sorted, dinv, bufA, b3, W4, bufB, N); // hs4
    agg_pool_kernel<<<gN8, TB, 0, stream>>>(row_start, src_sorted, dinv, bufB, b4, gs, N);       // pool(X5)

    head_kernel<<<1, 64, 0, stream>>>(gs, Wl1, bl1, Wl2, bl2, out);
}

// Round 9
// 508.030 us; speedup vs baseline: 1.3650x; 1.1816x over previous
//
#include <hip/hip_runtime.h>
#include <hip/hip_fp16.h>

#define F_IN 61
#define H 32
#define BUCK_BITS 8                  // 256 nodes per bucket
#define BUCK_SZ   256
#define CHUNK     8192               // edges per block in hist/bin passes

// ---------- degree / dinv ----------
__global__ __launch_bounds__(256) void deg_kernel(const int* __restrict__ ei,
                                                  int* __restrict__ deg, int E) {
    int e = blockIdx.x * 256 + threadIdx.x;
    if (e < E) atomicAdd(&deg[ei[E + e]], 1);
}

__global__ __launch_bounds__(256) void dinv_kernel(const int* __restrict__ deg,
                                                   float* __restrict__ dinv, int N) {
    int i = blockIdx.x * 256 + threadIdx.x;
    if (i < N) dinv[i] = rsqrtf((float)deg[i] + 1.0f);   // +1 self-loop
}

// ---------- generic 3-level exclusive scan ----------
__global__ __launch_bounds__(256) void scan1_kernel(const int* __restrict__ in,
                                                    int* __restrict__ scanned,
                                                    int* __restrict__ btot, int n) {
    __shared__ int s[256];
    int tid = threadIdx.x;
    int i = blockIdx.x * 256 + tid;
    int v = (i < n) ? in[i] : 0;
    s[tid] = v;
    __syncthreads();
    for (int off = 1; off < 256; off <<= 1) {
        int t = (tid >= off) ? s[tid - off] : 0;
        __syncthreads();
        s[tid] += t;
        __syncthreads();
    }
    if (i < n) scanned[i] = s[tid] - v;
    if (tid == 255) btot[blockIdx.x] = s[255];
}

__global__ __launch_bounds__(1024) void scan2_kernel(int* __restrict__ btot, int nB) {
    __shared__ int s[1024];
    int tid = threadIdx.x;
    int v = (tid < nB) ? btot[tid] : 0;
    s[tid] = v;
    __syncthreads();
    for (int off = 1; off < 1024; off <<= 1) {
        int t = (tid >= off) ? s[tid - off] : 0;
        __syncthreads();
        s[tid] += t;
        __syncthreads();
    }
    if (tid < nB) btot[tid] = s[tid] - v;
}

// node variant: writes row_start and the E tail
__global__ __launch_bounds__(256) void scan3_kernel(const int* __restrict__ scanned,
                                                    const int* __restrict__ btot,
                                                    int* __restrict__ row_start, int N, int E) {
    int i = blockIdx.x * 256 + threadIdx.x;
    if (i < N) row_start[i] = scanned[i] + btot[blockIdx.x];
    if (i == 0) row_start[N] = E;
}

// generic variant (in-place capable): out[i] = scanned[i] + btot[block]
__global__ __launch_bounds__(256) void scan3b_kernel(const int* __restrict__ scanned,
                                                     const int* __restrict__ btot,
                                                     int* __restrict__ outv, int n) {
    int i = blockIdx.x * 256 + threadIdx.x;
    if (i < n) outv[i] = scanned[i] + btot[blockIdx.x];
}

// ---------- pass A: per-(block,bucket) histogram ----------
__global__ __launch_bounds__(256) void histA_kernel(const int* __restrict__ ei,
                                                    int* __restrict__ counts,
                                                    int E, int B, int nbuck) {
    __shared__ int h[640];
    int tid = threadIdx.x;
    for (int i = tid; i < nbuck; i += 256) h[i] = 0;
    __syncthreads();
    int e0 = blockIdx.x * CHUNK;
    int e1 = e0 + CHUNK; if (e1 > E) e1 = E;
    for (int e = e0 + tid; e < e1; e += 256)
        atomicAdd(&h[ei[E + e] >> BUCK_BITS], 1);
    __syncthreads();
    for (int i = tid; i < nbuck; i += 256) counts[i * B + blockIdx.x] = h[i];
}

// ---------- pass B: bin edges into per-(block,bucket) EXCLUSIVE ranges ----------
// pack = (src<<8)|(dst&255); src < 2^18 fits.
__global__ __launch_bounds__(256) void binB_kernel(const int* __restrict__ ei,
                                                   const int* __restrict__ counts,
                                                   int* __restrict__ tmp,
                                                   int E, int B, int nbuck) {
    __shared__ int lcur[640];
    int tid = threadIdx.x;
    for (int i = tid; i < nbuck; i += 256) lcur[i] = counts[i * B + blockIdx.x];
    __syncthreads();
    int e0 = blockIdx.x * CHUNK;
    int e1 = e0 + CHUNK; if (e1 > E) e1 = E;
    for (int e = e0 + tid; e < e1; e += 256) {
        int s = ei[e];
        int d = ei[E + e];
        int pos = atomicAdd(&lcur[d >> BUCK_BITS], 1);
        tmp[pos] = (s << BUCK_BITS) | (d & (BUCK_SZ - 1));
    }
}

// ---------- pass C: per-bucket final CSR scatter (586 blocks) ----------
__global__ __launch_bounds__(256) void binC_kernel(const int* __restrict__ row_start,
                                                   const int* __restrict__ tmp,
                                                   int* __restrict__ src_sorted, int N) {
    __shared__ int lcur[BUCK_SZ];
    int tid = threadIdx.x;
    int base = blockIdx.x << BUCK_BITS;
    int nn = N - base; if (nn > BUCK_SZ) nn = BUCK_SZ;
    if (tid < nn) lcur[tid] = row_start[base + tid];
    __syncthreads();
    int hiNode = base + BUCK_SZ; if (hiNode > N) hiNode = N;
    int e0 = row_start[base];
    int e1 = row_start[hiNode];
    for (int e = e0 + tid; e < e1; e += 256) {
        int p = tmp[e];
        int pos = atomicAdd(&lcur[p & (BUCK_SZ - 1)], 1);
        src_sorted[pos] = p >> BUCK_BITS;
    }
}

// ---------- layer 1 dense: hs1 = fp16( dinv * (x @ W1) ) ----------
__global__ __launch_bounds__(256) void gemm1_kernel(const float* __restrict__ x,
                                                    const float* __restrict__ W,
                                                    const float* __restrict__ dinv,
                                                    __half* __restrict__ h, int N) {
    __shared__ float Ws[F_IN * H];
    __shared__ float xs[8 * F_IN];
    int tid = threadIdx.x;
    for (int i = tid; i < F_IN * H; i += 256) Ws[i] = W[i];
    int nb = blockIdx.x * 8;
    int navail = N - nb; if (navail > 8) navail = 8;
    const float* xb = x + (long long)nb * F_IN;
    for (int i = tid; i < navail * F_IN; i += 256) xs[i] = xb[i];
    __syncthreads();
    int nl = tid >> 5, f = tid & 31;
    int node = nb + nl;
    if (node < N) {
        float s = 0.f;
        #pragma unroll
        for (int k = 0; k < F_IN; k++) s += xs[nl * F_IN + k] * Ws[k * H + f];
        h[(long long)node * H + f] = __float2half(s * dinv[node]);
    }
}

// ---------- fused agg + GEMM (hs fp16, deep gather pipeline) ----------
// hs[v] = fp16(dinv[v]*h[v]).  X[d] = relu(dinv[d]*(sum hs[src] + hs[d]) + b)
// hout[d] = fp16( dinv[d] * (X[d] @ Wn) )
// Rows are 64B in fp16 -> each 32-lane gather touches ONE cache line.
__global__ __launch_bounds__(256) void agg_gemm_kernel(const int* __restrict__ row_start,
                                                       const int* __restrict__ src_sorted,
                                                       const float* __restrict__ dinv,
                                                       const __half* __restrict__ hs,
                                                       const float* __restrict__ b,
                                                       const float* __restrict__ Wn,
                                                       __half* __restrict__ hout, int N) {
    __shared__ float Ws[H * H];
    __shared__ float t[8 * H];
    int tid = threadIdx.x;
    for (int i = tid; i < H * H; i += 256) Ws[i] = Wn[i];
    int nl = tid >> 5, f = tid & 31;
    int node = blockIdx.x * 8 + nl;
    if (node < N) {
        float acc = __half2float(hs[(long long)node * H + f]);   // self-loop
        int e0 = row_start[node], e1 = row_start[node + 1];
        for (int base = e0; base < e1; base += 32) {
            int rem = e1 - base;
            int cnt = rem < 32 ? rem : 32;
            int idx = 0;
            if (f < rem) idx = src_sorted[base + f];      // coalesced, 1 instr
            for (int j = 0; j < cnt; j += 8) {
                float g[8];
                #pragma unroll
                for (int k = 0; k < 8; k++) {
                    int s = __shfl(idx, j + k, 32);       // row 0 if slot invalid
                    float v = __half2float(hs[(long long)s * H + f]);
                    g[k] = (j + k < cnt) ? v : 0.f;
                }
                acc += ((g[0] + g[1]) + (g[2] + g[3])) + ((g[4] + g[5]) + (g[6] + g[7]));
            }
        }
        t[nl * H + f] = fmaxf(dinv[node] * acc + b[f], 0.f);
    }
    __syncthreads();
    if (node < N) {
        float s = 0.f;
        #pragma unroll
        for (int k = 0; k < H; k++) s += t[nl * H + k] * Ws[k * H + f];
        hout[(long long)node * H + f] = __float2half(s * dinv[node]);
    }
}

// ---------- final layer: X5 = relu(...), pool into 64 spread copies ----------
__global__ __launch_bounds__(256) void agg_pool_kernel(const int* __restrict__ row_start,
                                                       const int* __restrict__ src_sorted,
                                                       const float* __restrict__ dinv,
                                                       const __half* __restrict__ hs,
                                                       const float* __restrict__ b,
                                                       float* __restrict__ gs, int N) {
    __shared__ float t[8 * H];
    int tid = threadIdx.x;
    int nl = tid >> 5, f = tid & 31;
    int node = blockIdx.x * 8 + nl;
    float val = 0.f;
    if (node < N) {
        float acc = __half2float(hs[(long long)node * H + f]);
        int e0 = row_start[node], e1 = row_start[node + 1];
        for (int base = e0; base < e1; base += 32) {
            int rem = e1 - base;
            int cnt = rem < 32 ? rem : 32;
            int idx = 0;
            if (f < rem) idx = src_sorted[base + f];
            for (int j = 0; j < cnt; j += 8) {
                float g[8];
                #pragma unroll
                for (int k = 0; k < 8; k++) {
                    int s = __shfl(idx, j + k, 32);
                    float v = __half2float(hs[(long long)s * H + f]);
                    g[k] = (j + k < cnt) ? v : 0.f;
                }
                acc += ((g[0] + g[1]) + (g[2] + g[3])) + ((g[4] + g[5]) + (g[6] + g[7]));
            }
        }
        val = fmaxf(dinv[node] * acc + b[f], 0.f);
    }
    t[nl * H + f] = val;
    __syncthreads();
    if (tid < H) {
        float s = 0.f;
        #pragma unroll
        for (int r = 0; r < 8; r++) s += t[r * H + tid];
        atomicAdd(&gs[(blockIdx.x & 63) * H + tid], s);
    }
}

// ---------- head ----------
__global__ __launch_bounds__(64) void head_kernel(const float* __restrict__ gs,
                                                  const float* __restrict__ Wl1,
                                                  const float* __restrict__ bl1,
                                                  const float* __restrict__ Wl2,
                                                  const float* __restrict__ bl2,
                                                  float* __restrict__ out) {
    __shared__ float gg[H];
    __shared__ float t[16];
    int tid = threadIdx.x;
    if (tid < H) {
        float s = 0.f;
        for (int c = 0; c < 64; c++) s += gs[c * H + tid];
        gg[tid] = s;
    }
    __syncthreads();
    if (tid < 16) {
        float s = bl1[tid];
        #pragma unroll
        for (int k = 0; k < 32; k++) s += gg[k] * Wl1[k * 16 + tid];
        t[tid] = fmaxf(s, 0.f);
    }
    __syncthreads();
    if (tid < 3) {
        float s = bl2[tid];
        #pragma unroll
        for (int k = 0; k < 16; k++) s += t[k] * Wl2[k * 3 + tid];
        out[tid] = s;
    }
}

extern "C" void kernel_launch(void* const* d_in, const int* in_sizes, int n_in,
                              void* d_out, int out_size, void* d_ws, size_t ws_size,
                              hipStream_t stream) {
    const float* x   = (const float*)d_in[0];
    const int*   ei  = (const int*)d_in[1];
    const float* W1  = (const float*)d_in[2];
    const float* b1  = (const float*)d_in[3];
    const float* W2  = (const float*)d_in[4];
    const float* b2  = (const float*)d_in[5];
    const float* W3  = (const float*)d_in[6];
    const float* b3  = (const float*)d_in[7];
    const float* W4  = (const float*)d_in[8];
    const float* b4  = (const float*)d_in[9];
    const float* Wl1 = (const float*)d_in[10];
    const float* bl1 = (const float*)d_in[11];
    const float* Wl2 = (const float*)d_in[12];
    const float* bl2 = (const float*)d_in[13];
    float* out = (float*)d_out;

    const int N = in_sizes[0] / F_IN;
    const int E = in_sizes[1] / 2;
    const int nbuck = (N + BUCK_SZ - 1) >> BUCK_BITS;      // 586 for N=150000
    const int B = (E + CHUNK - 1) / CHUNK;                 // 293 for E=2.4M
    const int nC = nbuck * B;                              // ~172k counts

    char* ws = (char*)d_ws;
    size_t off = 0;
    auto alloc = [&](size_t bytes) {
        char* p = ws + off;
        off += (bytes + 255) & ~(size_t)255;
        return p;
    };
    int*   deg        = (int*)alloc((size_t)N * 4);
    float* dinv       = (float*)alloc((size_t)N * 4);
    int*   scanned    = (int*)alloc((size_t)N * 4);
    int*   btot       = (int*)alloc(((size_t)N / 256 + 2) * 4);
    int*   row_start  = (int*)alloc((size_t)(N + 1) * 4);
    int*   counts     = (int*)alloc((size_t)nC * 4);
    int*   countsS    = (int*)alloc((size_t)nC * 4);
    int*   btot2      = (int*)alloc(((size_t)nC / 256 + 2) * 4);
    int*   src_sorted = (int*)alloc((size_t)E * 4);
    size_t bufBytes   = (size_t)N * H * 2;                 // fp16 h buffers
    size_t tmpBytes   = (size_t)E * 4;
    __half* bufA      = (__half*)alloc(bufBytes > tmpBytes ? bufBytes : tmpBytes);
    __half* bufB      = (__half*)alloc(bufBytes);
    float* gs         = (float*)alloc(64 * H * 4);
    int*   tmp        = (int*)bufA;    // pass-B scratch; dead before gemm1 writes bufA

    const int TB = 256;
    const int gE  = (E + TB - 1) / TB;
    const int gN  = (N + TB - 1) / TB;   // node-scan blocks (<=1024)
    const int gC  = (nC + TB - 1) / TB;  // counts-scan blocks (<=1024)
    const int gN8 = (N + 7) / 8;

    // ---- CSR build ----
    hipMemsetAsync(deg, 0, (size_t)N * 4, stream);
    hipMemsetAsync(gs, 0, 64 * H * 4, stream);
    deg_kernel<<<gE, TB, 0, stream>>>(ei, deg, E);
    dinv_kernel<<<gN, TB, 0, stream>>>(deg, dinv, N);
    scan1_kernel<<<gN, TB, 0, stream>>>(deg, scanned, btot, N);
    scan2_kernel<<<1, 1024, 0, stream>>>(btot, gN);
    scan3_kernel<<<gN, TB, 0, stream>>>(scanned, btot, row_start, N, E);
    histA_kernel<<<B, TB, 0, stream>>>(ei, counts, E, B, nbuck);
    scan1_kernel<<<gC, TB, 0, stream>>>(counts, countsS, btot2, nC);
    scan2_kernel<<<1, 1024, 0, stream>>>(btot2, gC);
    scan3b_kernel<<<gC, TB, 0, stream>>>(countsS, btot2, counts, nC);
    binB_kernel<<<B, TB, 0, stream>>>(ei, counts, tmp, E, B, nbuck);
    binC_kernel<<<nbuck, TB, 0, stream>>>(row_start, tmp, src_sorted, N);

    // ---- layers ----
    gemm1_kernel<<<gN8, TB, 0, stream>>>(x, W1, dinv, bufA, N);                                  // hs1
    agg_gemm_kernel<<<gN8, TB, 0, stream>>>(row_start, src_sorted, dinv, bufA, b1, W2, bufB, N); // hs2
    agg_gemm_kernel<<<gN8, TB, 0, stream>>>(row_start, src_sorted, dinv, bufB, b2, W3, bufA, N); // hs3
    agg_gemm_kernel<<<gN8, TB, 0, stream>>>(row_start, src_sorted, dinv, bufA, b3, W4, bufB, N); // hs4
    agg_pool_kernel<<<gN8, TB, 0, stream>>>(row_start, src_sorted, dinv, bufB, b4, gs, N);       // pool(X5)

    head_kernel<<<1, 64, 0, stream>>>(gs, Wl1, bl1, Wl2, bl2, out);
}

// Round 10
// 406.037 us; speedup vs baseline: 1.7079x; 1.2512x over previous
//
#include <hip/hip_runtime.h>
#include <hip/hip_fp16.h>

#define F_IN 61
#define H 32
#define BUCK_BITS 8                  // 256 nodes per bucket
#define BUCK_SZ   256
#define CHUNK     8192               // edges per block in hist/bin passes

// ---------- generic 3-level exclusive scan (for the counts array) ----------
__global__ __launch_bounds__(256) void scan1_kernel(const int* __restrict__ in,
                                                    int* __restrict__ scanned,
                                                    int* __restrict__ btot, int n) {
    __shared__ int s[256];
    int tid = threadIdx.x;
    int i = blockIdx.x * 256 + tid;
    int v = (i < n) ? in[i] : 0;
    s[tid] = v;
    __syncthreads();
    for (int off = 1; off < 256; off <<= 1) {
        int t = (tid >= off) ? s[tid - off] : 0;
        __syncthreads();
        s[tid] += t;
        __syncthreads();
    }
    if (i < n) scanned[i] = s[tid] - v;
    if (tid == 255) btot[blockIdx.x] = s[255];
}

__global__ __launch_bounds__(1024) void scan2_kernel(int* __restrict__ btot, int nB) {
    __shared__ int s[1024];
    int tid = threadIdx.x;
    int v = (tid < nB) ? btot[tid] : 0;
    s[tid] = v;
    __syncthreads();
    for (int off = 1; off < 1024; off <<= 1) {
        int t = (tid >= off) ? s[tid - off] : 0;
        __syncthreads();
        s[tid] += t;
        __syncthreads();
    }
    if (tid < nB) btot[tid] = s[tid] - v;
}

__global__ __launch_bounds__(256) void scan3b_kernel(const int* __restrict__ scanned,
                                                     const int* __restrict__ btot,
                                                     int* __restrict__ outv, int n) {
    int i = blockIdx.x * 256 + threadIdx.x;
    if (i < n) outv[i] = scanned[i] + btot[blockIdx.x];
}

// ---------- pass A: per-(block,bucket) histogram ----------
__global__ __launch_bounds__(256) void histA_kernel(const int* __restrict__ ei,
                                                    int* __restrict__ counts,
                                                    int E, int B, int nbuck) {
    __shared__ int h[640];
    int tid = threadIdx.x;
    for (int i = tid; i < nbuck; i += 256) h[i] = 0;
    __syncthreads();
    int e0 = blockIdx.x * CHUNK;
    int e1 = e0 + CHUNK; if (e1 > E) e1 = E;
    for (int e = e0 + tid; e < e1; e += 256)
        atomicAdd(&h[ei[E + e] >> BUCK_BITS], 1);
    __syncthreads();
    for (int i = tid; i < nbuck; i += 256) counts[i * B + blockIdx.x] = h[i];
}

// ---------- pass B: bin edges into per-(block,bucket) EXCLUSIVE ranges ----------
// pack = (src<<8)|(dst&255); src < 2^18 fits.
__global__ __launch_bounds__(256) void binB_kernel(const int* __restrict__ ei,
                                                   const int* __restrict__ counts,
                                                   int* __restrict__ tmp,
                                                   int E, int B, int nbuck) {
    __shared__ int lcur[640];
    int tid = threadIdx.x;
    for (int i = tid; i < nbuck; i += 256) lcur[i] = counts[i * B + blockIdx.x];
    __syncthreads();
    int e0 = blockIdx.x * CHUNK;
    int e1 = e0 + CHUNK; if (e1 > E) e1 = E;
    for (int e = e0 + tid; e < e1; e += 256) {
        int s = ei[e];
        int d = ei[E + e];
        int pos = atomicAdd(&lcur[d >> BUCK_BITS], 1);
        tmp[pos] = (s << BUCK_BITS) | (d & (BUCK_SZ - 1));
    }
}

// ---------- pass C: per-bucket degree + row_start + dinv + final CSR scatter ----------
// One block per bucket. Degrees come from an LDS histogram of the bucket's own
// edges (no global atomics at all); row_start/dinv writes are coalesced.
__global__ __launch_bounds__(256) void binC_kernel(const int* __restrict__ counts,
                                                   const int* __restrict__ tmp,
                                                   int* __restrict__ src_sorted,
                                                   int* __restrict__ row_start,
                                                   float* __restrict__ dinv,
                                                   int N, int E, int B, int nbuck) {
    __shared__ int hist[BUCK_SZ];
    __shared__ int pre[BUCK_SZ];
    __shared__ int lcur[BUCK_SZ];
    int tid = threadIdx.x;
    int b = blockIdx.x;
    int base = b << BUCK_BITS;
    int e0 = counts[b * B];
    int e1 = (b + 1 < nbuck) ? counts[(b + 1) * B] : E;
    hist[tid] = 0;
    __syncthreads();
    for (int e = e0 + tid; e < e1; e += 256)
        atomicAdd(&hist[tmp[e] & (BUCK_SZ - 1)], 1);
    __syncthreads();
    int v = hist[tid];
    pre[tid] = v;
    __syncthreads();
    for (int off = 1; off < 256; off <<= 1) {
        int t = (tid >= off) ? pre[tid - off] : 0;
        __syncthreads();
        pre[tid] += t;
        __syncthreads();
    }
    int excl = pre[tid] - v;
    int node = base + tid;
    if (node < N) {
        row_start[node] = e0 + excl;
        dinv[node] = rsqrtf((float)v + 1.0f);     // +1 self-loop
        if (node == N - 1) row_start[N] = E;
    }
    lcur[tid] = e0 + excl;
    __syncthreads();
    for (int e = e0 + tid; e < e1; e += 256) {
        int p = tmp[e];
        int pos = atomicAdd(&lcur[p & (BUCK_SZ - 1)], 1);
        src_sorted[pos] = p >> BUCK_BITS;
    }
}

// ---------- layer 1 dense: hs1 = fp16( dinv * (x @ W1) ) ----------
__global__ __launch_bounds__(256) void gemm1_kernel(const float* __restrict__ x,
                                                    const float* __restrict__ W,
                                                    const float* __restrict__ dinv,
                                                    __half* __restrict__ h, int N) {
    __shared__ float Ws[F_IN * H];
    __shared__ float xs[8 * F_IN];
    int tid = threadIdx.x;
    for (int i = tid; i < F_IN * H; i += 256) Ws[i] = W[i];
    int nb = blockIdx.x * 8;
    int navail = N - nb; if (navail > 8) navail = 8;
    const float* xb = x + (long long)nb * F_IN;
    for (int i = tid; i < navail * F_IN; i += 256) xs[i] = xb[i];
    __syncthreads();
    int nl = tid >> 5, f = tid & 31;
    int node = nb + nl;
    if (node < N) {
        float s = 0.f;
        #pragma unroll
        for (int k = 0; k < F_IN; k++) s += xs[nl * F_IN + k] * Ws[k * H + f];
        h[(long long)node * H + f] = __float2half(s * dinv[node]);
    }
}

// ---------- fused agg + GEMM (hs fp16, prefetched idx, 16-deep gathers) ----------
__global__ __launch_bounds__(256) void agg_gemm_kernel(const int* __restrict__ row_start,
                                                       const int* __restrict__ src_sorted,
                                                       const float* __restrict__ dinv,
                                                       const __half* __restrict__ hs,
                                                       const float* __restrict__ b,
                                                       const float* __restrict__ Wn,
                                                       __half* __restrict__ hout, int N) {
    __shared__ float Ws[H * H];
    __shared__ float t[8 * H];
    int tid = threadIdx.x;
    for (int i = tid; i < H * H; i += 256) Ws[i] = Wn[i];
    int nl = tid >> 5, f = tid & 31;
    int node = blockIdx.x * 8 + nl;
    if (node < N) {
        const __half* hrow = hs + f;
        float acc = __half2float(hrow[(long long)node * H]);   // self-loop
        int e0 = row_start[node], e1 = row_start[node + 1];
        int idx = (e0 + f < e1) ? src_sorted[e0 + f] : 0;
        for (int base = e0; base < e1; base += 32) {
            int rem = e1 - base;
            int cnt = rem < 32 ? rem : 32;
            int idxN = (base + 32 + f < e1) ? src_sorted[base + 32 + f] : 0;  // prefetch
            for (int j = 0; j < cnt; j += 16) {
                float g[16];
                #pragma unroll
                for (int k = 0; k < 16; k++) {
                    int s = __shfl(idx, j + k, 32);            // row 0 if invalid
                    float vv = __half2float(hrow[(long long)s * H]);
                    g[k] = (j + k < cnt) ? vv : 0.f;
                }
                float s0 = ((g[0] + g[1]) + (g[2] + g[3])) + ((g[4] + g[5]) + (g[6] + g[7]));
                float s1 = ((g[8] + g[9]) + (g[10] + g[11])) + ((g[12] + g[13]) + (g[14] + g[15]));
                acc += s0 + s1;
            }
            idx = idxN;
        }
        t[nl * H + f] = fmaxf(dinv[node] * acc + b[f], 0.f);
    }
    __syncthreads();
    if (node < N) {
        float s = 0.f;
        #pragma unroll
        for (int k = 0; k < H; k++) s += t[nl * H + k] * Ws[k * H + f];
        hout[(long long)node * H + f] = __float2half(s * dinv[node]);
    }
}

// ---------- final layer: X5 = relu(...), pool into 64 spread copies ----------
__global__ __launch_bounds__(256) void agg_pool_kernel(const int* __restrict__ row_start,
                                                       const int* __restrict__ src_sorted,
                                                       const float* __restrict__ dinv,
                                                       const __half* __restrict__ hs,
                                                       const float* __restrict__ b,
                                                       float* __restrict__ gs, int N) {
    __shared__ float t[8 * H];
    int tid = threadIdx.x;
    int nl = tid >> 5, f = tid & 31;
    int node = blockIdx.x * 8 + nl;
    float val = 0.f;
    if (node < N) {
        const __half* hrow = hs + f;
        float acc = __half2float(hrow[(long long)node * H]);
        int e0 = row_start[node], e1 = row_start[node + 1];
        int idx = (e0 + f < e1) ? src_sorted[e0 + f] : 0;
        for (int base = e0; base < e1; base += 32) {
            int rem = e1 - base;
            int cnt = rem < 32 ? rem : 32;
            int idxN = (base + 32 + f < e1) ? src_sorted[base + 32 + f] : 0;
            for (int j = 0; j < cnt; j += 16) {
                float g[16];
                #pragma unroll
                for (int k = 0; k < 16; k++) {
                    int s = __shfl(idx, j + k, 32);
                    float vv = __half2float(hrow[(long long)s * H]);
                    g[k] = (j + k < cnt) ? vv : 0.f;
                }
                float s0 = ((g[0] + g[1]) + (g[2] + g[3])) + ((g[4] + g[5]) + (g[6] + g[7]));
                float s1 = ((g[8] + g[9]) + (g[10] + g[11])) + ((g[12] + g[13]) + (g[14] + g[15]));
                acc += s0 + s1;
            }
            idx = idxN;
        }
        val = fmaxf(dinv[node] * acc + b[f], 0.f);
    }
    t[nl * H + f] = val;
    __syncthreads();
    if (tid < H) {
        float s = 0.f;
        #pragma unroll
        for (int r = 0; r < 8; r++) s += t[r * H + tid];
        atomicAdd(&gs[(blockIdx.x & 63) * H + tid], s);
    }
}

// ---------- head ----------
__global__ __launch_bounds__(64) void head_kernel(const float* __restrict__ gs,
                                                  const float* __restrict__ Wl1,
                                                  const float* __restrict__ bl1,
                                                  const float* __restrict__ Wl2,
                                                  const float* __restrict__ bl2,
                                                  float* __restrict__ out) {
    __shared__ float gg[H];
    __shared__ float t[16];
    int tid = threadIdx.x;
    if (tid < H) {
        float s = 0.f;
        for (int c = 0; c < 64; c++) s += gs[c * H + tid];
        gg[tid] = s;
    }
    __syncthreads();
    if (tid < 16) {
        float s = bl1[tid];
        #pragma unroll
        for (int k = 0; k < 32; k++) s += gg[k] * Wl1[k * 16 + tid];
        t[tid] = fmaxf(s, 0.f);
    }
    __syncthreads();
    if (tid < 3) {
        float s = bl2[tid];
        #pragma unroll
        for (int k = 0; k < 16; k++) s += t[k] * Wl2[k * 3 + tid];
        out[tid] = s;
    }
}

extern "C" void kernel_launch(void* const* d_in, const int* in_sizes, int n_in,
                              void* d_out, int out_size, void* d_ws, size_t ws_size,
                              hipStream_t stream) {
    const float* x   = (const float*)d_in[0];
    const int*   ei  = (const int*)d_in[1];
    const float* W1  = (const float*)d_in[2];
    const float* b1  = (const float*)d_in[3];
    const float* W2  = (const float*)d_in[4];
    const float* b2  = (const float*)d_in[5];
    const float* W3  = (const float*)d_in[6];
    const float* b3  = (const float*)d_in[7];
    const float* W4  = (const float*)d_in[8];
    const float* b4  = (const float*)d_in[9];
    const float* Wl1 = (const float*)d_in[10];
    const float* bl1 = (const float*)d_in[11];
    const float* Wl2 = (const float*)d_in[12];
    const float* bl2 = (const float*)d_in[13];
    float* out = (float*)d_out;

    const int N = in_sizes[0] / F_IN;
    const int E = in_sizes[1] / 2;
    const int nbuck = (N + BUCK_SZ - 1) >> BUCK_BITS;      // 586 for N=150000
    const int B = (E + CHUNK - 1) / CHUNK;                 // 293 for E=2.4M
    const int nC = nbuck * B;                              // ~172k counts

    char* ws = (char*)d_ws;
    size_t off = 0;
    auto alloc = [&](size_t bytes) {
        char* p = ws + off;
        off += (bytes + 255) & ~(size_t)255;
        return p;
    };
    float* dinv       = (float*)alloc((size_t)N * 4);
    int*   row_start  = (int*)alloc((size_t)(N + 1) * 4);
    int*   counts     = (int*)alloc((size_t)nC * 4);
    int*   countsS    = (int*)alloc((size_t)nC * 4);
    int*   btot2      = (int*)alloc(((size_t)nC / 256 + 2) * 4);
    int*   src_sorted = (int*)alloc((size_t)E * 4);
    size_t bufBytes   = (size_t)N * H * 2;                 // fp16 h buffers
    size_t tmpBytes   = (size_t)E * 4;
    __half* bufA      = (__half*)alloc(bufBytes > tmpBytes ? bufBytes : tmpBytes);
    __half* bufB      = (__half*)alloc(bufBytes);
    float* gs         = (float*)alloc(64 * H * 4);
    int*   tmp        = (int*)bufA;    // pass-B scratch; dead before gemm1 writes bufA

    const int TB = 256;
    const int gC  = (nC + TB - 1) / TB;  // counts-scan blocks (<=1024)
    const int gN8 = (N + 7) / 8;

    // ---- CSR build (no global atomics anywhere) ----
    hipMemsetAsync(gs, 0, 64 * H * 4, stream);
    histA_kernel<<<B, TB, 0, stream>>>(ei, counts, E, B, nbuck);
    scan1_kernel<<<gC, TB, 0, stream>>>(counts, countsS, btot2, nC);
    scan2_kernel<<<1, 1024, 0, stream>>>(btot2, gC);
    scan3b_kernel<<<gC, TB, 0, stream>>>(countsS, btot2, counts, nC);
    binB_kernel<<<B, TB, 0, stream>>>(ei, counts, tmp, E, B, nbuck);
    binC_kernel<<<nbuck, TB, 0, stream>>>(counts, tmp, src_sorted, row_start, dinv,
                                          N, E, B, nbuck);

    // ---- layers ----
    gemm1_kernel<<<gN8, TB, 0, stream>>>(x, W1, dinv, bufA, N);                                  // hs1
    agg_gemm_kernel<<<gN8, TB, 0, stream>>>(row_start, src_sorted, dinv, bufA, b1, W2, bufB, N); // hs2
    agg_gemm_kernel<<<gN8, TB, 0, stream>>>(row_start, src_sorted, dinv, bufB, b2, W3, bufA, N); // hs3
    agg_gemm_kernel<<<gN8, TB, 0, stream>>>(row_start, src_sorted, dinv, bufA, b3, W4, bufB, N); // hs4
    agg_pool_kernel<<<gN8, TB, 0, stream>>>(row_start, src_sorted, dinv, bufB, b4, gs, N);       // pool(X5)

    head_kernel<<<1, 64, 0, stream>>>(gs, Wl1, bl1, Wl2, bl2, out);
}

// Round 11
// 396.996 us; speedup vs baseline: 1.7468x; 1.0228x over previous
//
#include <hip/hip_runtime.h>
#include <hip/hip_fp16.h>

#define F_IN 61
#define H 32
#define BUCK_BITS 8                  // 256 nodes per bucket
#define BUCK_SZ   256
#define CHUNK     16384              // edges per block in hist/bin passes

// ---------- generic 3-level exclusive scan (for the counts array) ----------
__global__ __launch_bounds__(256) void scan1_kernel(const int* __restrict__ in,
                                                    int* __restrict__ scanned,
                                                    int* __restrict__ btot, int n) {
    __shared__ int s[256];
    int tid = threadIdx.x;
    int i = blockIdx.x * 256 + tid;
    int v = (i < n) ? in[i] : 0;
    s[tid] = v;
    __syncthreads();
    for (int off = 1; off < 256; off <<= 1) {
        int t = (tid >= off) ? s[tid - off] : 0;
        __syncthreads();
        s[tid] += t;
        __syncthreads();
    }
    if (i < n) scanned[i] = s[tid] - v;
    if (tid == 255) btot[blockIdx.x] = s[255];
}

__global__ __launch_bounds__(1024) void scan2_kernel(int* __restrict__ btot, int nB) {
    __shared__ int s[1024];
    int tid = threadIdx.x;
    int v = (tid < nB) ? btot[tid] : 0;
    s[tid] = v;
    __syncthreads();
    for (int off = 1; off < 1024; off <<= 1) {
        int t = (tid >= off) ? s[tid - off] : 0;
        __syncthreads();
        s[tid] += t;
        __syncthreads();
    }
    if (tid < nB) btot[tid] = s[tid] - v;
}

__global__ __launch_bounds__(256) void scan3b_kernel(const int* __restrict__ scanned,
                                                     const int* __restrict__ btot,
                                                     int* __restrict__ outv, int n) {
    int i = blockIdx.x * 256 + threadIdx.x;
    if (i < n) outv[i] = scanned[i] + btot[blockIdx.x];
}

// ---------- pass A: per-(block,bucket) histogram ----------
__global__ __launch_bounds__(256) void histA_kernel(const int* __restrict__ ei,
                                                    int* __restrict__ counts,
                                                    int E, int B, int nbuck) {
    __shared__ int h[640];
    int tid = threadIdx.x;
    for (int i = tid; i < nbuck; i += 256) h[i] = 0;
    __syncthreads();
    int e0 = blockIdx.x * CHUNK;
    int e1 = e0 + CHUNK; if (e1 > E) e1 = E;
    for (int e = e0 + tid; e < e1; e += 256)
        atomicAdd(&h[ei[E + e] >> BUCK_BITS], 1);
    __syncthreads();
    for (int i = tid; i < nbuck; i += 256) counts[i * B + blockIdx.x] = h[i];
}

// ---------- pass B: bin edges into per-(block,bucket) EXCLUSIVE ranges ----------
// pack = (src<<8)|(dst&255); src < 2^18 fits.
__global__ __launch_bounds__(256) void binB_kernel(const int* __restrict__ ei,
                                                   const int* __restrict__ counts,
                                                   int* __restrict__ tmp,
                                                   int E, int B, int nbuck) {
    __shared__ int lcur[640];
    int tid = threadIdx.x;
    for (int i = tid; i < nbuck; i += 256) lcur[i] = counts[i * B + blockIdx.x];
    __syncthreads();
    int e0 = blockIdx.x * CHUNK;
    int e1 = e0 + CHUNK; if (e1 > E) e1 = E;
    for (int e = e0 + tid; e < e1; e += 256) {
        int s = ei[e];
        int d = ei[E + e];
        int pos = atomicAdd(&lcur[d >> BUCK_BITS], 1);
        tmp[pos] = (s << BUCK_BITS) | (d & (BUCK_SZ - 1));
    }
}

// ---------- pass C: per-bucket degree + row_start + dinv + final CSR scatter ----------
// src_sorted stores BYTE offsets (src*64) for the fp16 row table.
__global__ __launch_bounds__(256) void binC_kernel(const int* __restrict__ counts,
                                                   const int* __restrict__ tmp,
                                                   int* __restrict__ src_sorted,
                                                   int* __restrict__ row_start,
                                                   float* __restrict__ dinv,
                                                   int N, int E, int B, int nbuck) {
    __shared__ int hist[BUCK_SZ];
    __shared__ int pre[BUCK_SZ];
    __shared__ int lcur[BUCK_SZ];
    int tid = threadIdx.x;
    int b = blockIdx.x;
    int base = b << BUCK_BITS;
    int e0 = counts[b * B];
    int e1 = (b + 1 < nbuck) ? counts[(b + 1) * B] : E;
    hist[tid] = 0;
    __syncthreads();
    for (int e = e0 + tid; e < e1; e += 256)
        atomicAdd(&hist[tmp[e] & (BUCK_SZ - 1)], 1);
    __syncthreads();
    int v = hist[tid];
    pre[tid] = v;
    __syncthreads();
    for (int off = 1; off < 256; off <<= 1) {
        int t = (tid >= off) ? pre[tid - off] : 0;
        __syncthreads();
        pre[tid] += t;
        __syncthreads();
    }
    int excl = pre[tid] - v;
    int node = base + tid;
    if (node < N) {
        row_start[node] = e0 + excl;
        dinv[node] = rsqrtf((float)v + 1.0f);     // +1 self-loop
        if (node == N - 1) row_start[N] = E;
    }
    lcur[tid] = e0 + excl;
    __syncthreads();
    for (int e = e0 + tid; e < e1; e += 256) {
        int p = tmp[e];
        int pos = atomicAdd(&lcur[p & (BUCK_SZ - 1)], 1);
        src_sorted[pos] = (p >> BUCK_BITS) << 6;   // byte offset of fp16 row
    }
}

// ---------- layer 1 dense: hs1 = fp16( dinv * (x @ W1) ) ----------
__global__ __launch_bounds__(256) void gemm1_kernel(const float* __restrict__ x,
                                                    const float* __restrict__ W,
                                                    const float* __restrict__ dinv,
                                                    __half* __restrict__ h, int N) {
    __shared__ float Ws[F_IN * H];
    __shared__ float xs[8 * F_IN];
    int tid = threadIdx.x;
    for (int i = tid; i < F_IN * H; i += 256) Ws[i] = W[i];
    int nb = blockIdx.x * 8;
    int navail = N - nb; if (navail > 8) navail = 8;
    const float* xb = x + (long long)nb * F_IN;
    for (int i = tid; i < navail * F_IN; i += 256) xs[i] = xb[i];
    __syncthreads();
    int nl = tid >> 5, f = tid & 31;
    int node = nb + nl;
    if (node < N) {
        float s = 0.f;
        #pragma unroll
        for (int k = 0; k < F_IN; k++) s += xs[nl * F_IN + k] * Ws[k * H + f];
        h[(long long)node * H + f] = __float2half(s * dinv[node]);
    }
}

// ---------- fused agg + GEMM (half2 gathers: 2 edges per load instr) ----------
// Lane map per node (32 lanes): p = lane>>4 (edge parity), fp = lane&15
// (feature pair). Each lane gathers __half2 {2fp,2fp+1} of edge slot j+2k+p.
// Invalid slots gather the dedicated ZERO ROW at byte offset N*64.
__global__ __launch_bounds__(256) void agg_gemm_kernel(const int* __restrict__ row_start,
                                                       const int* __restrict__ src_sorted,
                                                       const float* __restrict__ dinv,
                                                       const __half* __restrict__ hs,
                                                       const float* __restrict__ b,
                                                       const float* __restrict__ Wn,
                                                       __half* __restrict__ hout, int N) {
    __shared__ float Ws[H * H];
    __shared__ float t[8 * H];
    int tid = threadIdx.x;
    for (int i = tid; i < H * H; i += 256) Ws[i] = Wn[i];
    int nl = tid >> 5;
    int lane32 = tid & 31;
    int p = lane32 >> 4;
    int fp = lane32 & 15;
    int node = blockIdx.x * 8 + nl;
    int zoff = N << 6;
    float2 acc = make_float2(0.f, 0.f);
    if (node < N) {
        const char* hbase = (const char*)hs + (fp << 2);
        int e0 = row_start[node], e1 = row_start[node + 1];
        int idxv = (e0 + lane32 < e1) ? src_sorted[e0 + lane32] : zoff;
        for (int base = e0; base < e1; base += 32) {
            int w = e1 - base; if (w > 32) w = 32;
            int idxN = (base + 32 + lane32 < e1) ? src_sorted[base + 32 + lane32] : zoff;
            for (int j = 0; j < w; j += 16) {
                int offs[8];
                #pragma unroll
                for (int k = 0; k < 8; k++) offs[k] = __shfl(idxv, j + 2 * k + p, 32);
                unsigned g[8];
                #pragma unroll
                for (int k = 0; k < 8; k++) g[k] = *(const unsigned*)(hbase + offs[k]);
                #pragma unroll
                for (int k = 0; k < 8; k++) {
                    float2 fv = __half22float2(*(__half2*)&g[k]);
                    acc.x += fv.x; acc.y += fv.y;
                }
            }
            idxv = idxN;
        }
    }
    acc.x += __shfl_xor(acc.x, 16, 32);
    acc.y += __shfl_xor(acc.y, 16, 32);
    if (node < N && p == 0) {
        float di = dinv[node];
        float2 s2 = __half22float2(*(const __half2*)((const char*)hs +
                          ((long long)node << 6) + (fp << 2)));
        float2 bv = ((const float2*)b)[fp];
        float rx = fmaxf(di * (acc.x + s2.x) + bv.x, 0.f);
        float ry = fmaxf(di * (acc.y + s2.y) + bv.y, 0.f);
        ((float2*)&t[nl * H])[fp] = make_float2(rx, ry);
    }
    __syncthreads();
    if (node < N) {
        int f = lane32;
        float s = 0.f;
        #pragma unroll
        for (int k = 0; k < H; k++) s += t[nl * H + k] * Ws[k * H + f];
        hout[(long long)node * H + f] = __float2half(s * dinv[node]);
    }
}

// ---------- final layer: X5 = relu(...), pool into 64 spread copies ----------
__global__ __launch_bounds__(256) void agg_pool_kernel(const int* __restrict__ row_start,
                                                       const int* __restrict__ src_sorted,
                                                       const float* __restrict__ dinv,
                                                       const __half* __restrict__ hs,
                                                       const float* __restrict__ b,
                                                       float* __restrict__ gs, int N) {
    __shared__ float t[8 * H];
    int tid = threadIdx.x;
    int nl = tid >> 5;
    int lane32 = tid & 31;
    int p = lane32 >> 4;
    int fp = lane32 & 15;
    int node = blockIdx.x * 8 + nl;
    int zoff = N << 6;
    float2 acc = make_float2(0.f, 0.f);
    if (node < N) {
        const char* hbase = (const char*)hs + (fp << 2);
        int e0 = row_start[node], e1 = row_start[node + 1];
        int idxv = (e0 + lane32 < e1) ? src_sorted[e0 + lane32] : zoff;
        for (int base = e0; base < e1; base += 32) {
            int w = e1 - base; if (w > 32) w = 32;
            int idxN = (base + 32 + lane32 < e1) ? src_sorted[base + 32 + lane32] : zoff;
            for (int j = 0; j < w; j += 16) {
                int offs[8];
                #pragma unroll
                for (int k = 0; k < 8; k++) offs[k] = __shfl(idxv, j + 2 * k + p, 32);
                unsigned g[8];
                #pragma unroll
                for (int k = 0; k < 8; k++) g[k] = *(const unsigned*)(hbase + offs[k]);
                #pragma unroll
                for (int k = 0; k < 8; k++) {
                    float2 fv = __half22float2(*(__half2*)&g[k]);
                    acc.x += fv.x; acc.y += fv.y;
                }
            }
            idxv = idxN;
        }
    }
    acc.x += __shfl_xor(acc.x, 16, 32);
    acc.y += __shfl_xor(acc.y, 16, 32);
    float2 r = make_float2(0.f, 0.f);
    if (node < N && p == 0) {
        float di = dinv[node];
        float2 s2 = __half22float2(*(const __half2*)((const char*)hs +
                          ((long long)node << 6) + (fp << 2)));
        float2 bv = ((const float2*)b)[fp];
        r.x = fmaxf(di * (acc.x + s2.x) + bv.x, 0.f);
        r.y = fmaxf(di * (acc.y + s2.y) + bv.y, 0.f);
    }
    if (p == 0) ((float2*)&t[nl * H])[fp] = r;
    __syncthreads();
    if (tid < H) {
        float s = 0.f;
        #pragma unroll
        for (int rI = 0; rI < 8; rI++) s += t[rI * H + tid];
        atomicAdd(&gs[(blockIdx.x & 63) * H + tid], s);
    }
}

// ---------- head ----------
__global__ __launch_bounds__(64) void head_kernel(const float* __restrict__ gs,
                                                  const float* __restrict__ Wl1,
                                                  const float* __restrict__ bl1,
                                                  const float* __restrict__ Wl2,
                                                  const float* __restrict__ bl2,
                                                  float* __restrict__ out) {
    __shared__ float gg[H];
    __shared__ float t[16];
    int tid = threadIdx.x;
    if (tid < H) {
        float s = 0.f;
        for (int c = 0; c < 64; c++) s += gs[c * H + tid];
        gg[tid] = s;
    }
    __syncthreads();
    if (tid < 16) {
        float s = bl1[tid];
        #pragma unroll
        for (int k = 0; k < 32; k++) s += gg[k] * Wl1[k * 16 + tid];
        t[tid] = fmaxf(s, 0.f);
    }
    __syncthreads();
    if (tid < 3) {
        float s = bl2[tid];
        #pragma unroll
        for (int k = 0; k < 16; k++) s += t[k] * Wl2[k * 3 + tid];
        out[tid] = s;
    }
}

extern "C" void kernel_launch(void* const* d_in, const int* in_sizes, int n_in,
                              void* d_out, int out_size, void* d_ws, size_t ws_size,
                              hipStream_t stream) {
    const float* x   = (const float*)d_in[0];
    const int*   ei  = (const int*)d_in[1];
    const float* W1  = (const float*)d_in[2];
    const float* b1  = (const float*)d_in[3];
    const float* W2  = (const float*)d_in[4];
    const float* b2  = (const float*)d_in[5];
    const float* W3  = (const float*)d_in[6];
    const float* b3  = (const float*)d_in[7];
    const float* W4  = (const float*)d_in[8];
    const float* b4  = (const float*)d_in[9];
    const float* Wl1 = (const float*)d_in[10];
    const float* bl1 = (const float*)d_in[11];
    const float* Wl2 = (const float*)d_in[12];
    const float* bl2 = (const float*)d_in[13];
    float* out = (float*)d_out;

    const int N = in_sizes[0] / F_IN;
    const int E = in_sizes[1] / 2;
    const int nbuck = (N + BUCK_SZ - 1) >> BUCK_BITS;      // 586 for N=150000
    const int B = (E + CHUNK - 1) / CHUNK;                 // 147 for E=2.4M
    const int nC = nbuck * B;                              // ~86k counts

    char* ws = (char*)d_ws;
    size_t off = 0;
    auto alloc = [&](size_t bytes) {
        char* p = ws + off;
        off += (bytes + 255) & ~(size_t)255;
        return p;
    };
    float* dinv       = (float*)alloc((size_t)N * 4);
    int*   row_start  = (int*)alloc((size_t)(N + 1) * 4);
    int*   counts     = (int*)alloc((size_t)nC * 4);
    int*   countsS    = (int*)alloc((size_t)nC * 4);
    int*   btot2      = (int*)alloc(((size_t)nC / 256 + 2) * 4);
    int*   src_sorted = (int*)alloc((size_t)E * 4);
    size_t bufBytes   = (size_t)(N + 1) * H * 2;           // fp16 rows + zero row
    size_t tmpBytes   = (size_t)E * 4;
    __half* bufA      = (__half*)alloc(bufBytes > tmpBytes ? bufBytes : tmpBytes);
    __half* bufB      = (__half*)alloc(bufBytes);
    float* gs         = (float*)alloc(64 * H * 4);
    int*   tmp        = (int*)bufA;    // pass-B scratch; dead after binC

    const int TB = 256;
    const int gC  = (nC + TB - 1) / TB;
    const int gN8 = (N + 7) / 8;

    // ---- CSR build (no global atomics anywhere) ----
    hipMemsetAsync(gs, 0, 64 * H * 4, stream);
    histA_kernel<<<B, TB, 0, stream>>>(ei, counts, E, B, nbuck);
    scan1_kernel<<<gC, TB, 0, stream>>>(counts, countsS, btot2, nC);
    scan2_kernel<<<1, 1024, 0, stream>>>(btot2, gC);
    scan3b_kernel<<<gC, TB, 0, stream>>>(countsS, btot2, counts, nC);
    binB_kernel<<<B, TB, 0, stream>>>(ei, counts, tmp, E, B, nbuck);
    binC_kernel<<<nbuck, TB, 0, stream>>>(counts, tmp, src_sorted, row_start, dinv,
                                          N, E, B, nbuck);
    // zero rows (index N) for the padded gathers; after binC (bufA aliased tmp)
    hipMemsetAsync(bufA + (size_t)N * H, 0, H * 2, stream);
    hipMemsetAsync(bufB + (size_t)N * H, 0, H * 2, stream);

    // ---- layers ----
    gemm1_kernel<<<gN8, TB, 0, stream>>>(x, W1, dinv, bufA, N);                                  // hs1
    agg_gemm_kernel<<<gN8, TB, 0, stream>>>(row_start, src_sorted, dinv, bufA, b1, W2, bufB, N); // hs2
    agg_gemm_kernel<<<gN8, TB, 0, stream>>>(row_start, src_sorted, dinv, bufB, b2, W3, bufA, N); // hs3
    agg_gemm_kernel<<<gN8, TB, 0, stream>>>(row_start, src_sorted, dinv, bufA, b3, W4, bufB, N); // hs4
    agg_pool_kernel<<<gN8, TB, 0, stream>>>(row_start, src_sorted, dinv, bufB, b4, gs, N);       // pool(X5)

    head_kernel<<<1, 64, 0, stream>>>(gs, Wl1, bl1, Wl2, bl2, out);
}